// Round 8
// baseline (5538.543 us; speedup 1.0000x reference)
//
#include <hip/hip_runtime.h>
#include <hip/hip_fp16.h>

// Wavefront-pipelined 20-layer ReLU RNN for MI355X — round 20.
// Lesson r19: flag sync with multi-load polls + 8-wave degree is WORSE than
// s_barrier (+1000cy/step). The fix is not the sync primitive, it's the SYNC
// DEGREE: r12's 8-wave n-split forces a full-block rendezvous every step.
// This round: the h-GEMM is split across only TWO waves (nt=8, 128 cols each,
// wf=256 VGPR, 1 wave/SIMD via TPB=256+launch_bounds(,1)). Per step each
// h-wave: reads its OWN k-half (self-written, zero wait) -> 32 MFMA, polls
// the single partner flag (1 x b32, overlapped behind own MFMAs), reads the
// partner half -> 32 MFMA, epilogue, write, flag. Sync degree 8 -> 1.
// Two X-waves run r19's proven superstep-cadence machinery: lane-contiguous
// exports (WRITE_SIZE halved - kept), half-slot staging ping-pong, XP GEMM
// lead-1 into xps[2], all remote protocol; sleepy spins off the h path.
// Numerics: same MFMA/rounding structure as r12; wave1 accumulates k own-
// half-first (f32 reassociation only) -> absmax may shift ~1e-6.

#define B_    128
#define T_    784
#define H_    256
#define L_    20
#define C_    10
#define G_    8      // batch slices
#define BM_   16     // batch rows per block
#define S_    4      // timesteps per superstep / ring slot
#define NS_   196    // T_/S_
#define SW_   264    // lH/bufX row stride in halves
#define XSW_  260    // xps row stride in halves
#define RQWS_ 4096   // u64 words per ring slot (4 steps x 16 rows x 64 u64)
#define TPB_  256
#define NTH_  8      // n-tiles per wave (128 cols)

typedef _Float16 v8h __attribute__((ext_vector_type(8)));
typedef _Float16 v4h __attribute__((ext_vector_type(4)));
typedef float    v4f __attribute__((ext_vector_type(4)));
typedef unsigned long long u64;

union U64H { u64 u; _Float16 h[4]; };

// flag indices in flg[16] (pairs at even offsets -> 8B aligned)
#define F_HF 0    // hflag[2]: h-wave w finished step t -> t+1
#define F_XP 2    // xpdone[2]: xps for superstep q ready -> q+1
#define F_XD 4    // xdone[2]: export reads of slot sg-1 done -> sg+1
#define F_XS 6    // staging halves of slot q -> 2q+1, 2q+2
#define F_XC 8    // computes of half A of slot q -> q+1
#define F_XE 10   // all computes of slot q -> q+1
#define F_XV 12   // vm-drained iteration sg -> sg+1

__device__ __forceinline__ void lgkm0() { asm volatile("s_waitcnt lgkmcnt(0)" ::: "memory"); }
__device__ __forceinline__ void vm0()   { asm volatile("s_waitcnt vmcnt(0)"   ::: "memory"); }
__device__ __forceinline__ void cbar()  { asm volatile("" ::: "memory"); }

__device__ __forceinline__ void flagst(unsigned* p, unsigned v) {
    cbar();
    __hip_atomic_store(p, v, __ATOMIC_RELAXED, __HIP_MEMORY_SCOPE_WORKGROUP);
}
// single-flag tight spin (h partner): ONE b32 load per iteration
__device__ __forceinline__ void spin1(const unsigned* f, unsigned tgt) {
    const volatile unsigned* p = (const volatile unsigned*)f;
    while (*p < tgt) {}
    cbar();
}
// pair spin: ONE b64 load per iteration
__device__ __forceinline__ void spin2(const unsigned* f, unsigned tgt) {
    const volatile u64* p = (const volatile u64*)f;
    for (;;) {
        u64 a = *p;
        if ((unsigned)a >= tgt && (unsigned)(a >> 32) >= tgt) break;
    }
    cbar();
}
__device__ __forceinline__ void spin2s(const unsigned* f, unsigned tgt) {
    const volatile u64* p = (const volatile u64*)f;
    for (;;) {
        u64 a = *p;
        if ((unsigned)a >= tgt && (unsigned)(a >> 32) >= tgt) break;
        __builtin_amdgcn_s_sleep(1);
    }
    cbar();
}
__device__ __forceinline__ u64 ringld(const u64* p) {
    return __hip_atomic_load(p, __ATOMIC_RELAXED, __HIP_MEMORY_SCOPE_AGENT);
}
__device__ __forceinline__ void ringst(u64* p, u64 v) {
    __hip_atomic_store(p, v, __ATOMIC_RELAXED, __HIP_MEMORY_SCOPE_AGENT);
}
__device__ __forceinline__ unsigned remld(const unsigned* p) {
    return __hip_atomic_load(p, __ATOMIC_RELAXED, __HIP_MEMORY_SCOPE_AGENT);
}
__device__ __forceinline__ void rempub(unsigned* p, unsigned v) {
    __hip_atomic_store(p, v, __ATOMIC_RELAXED, __HIP_MEMORY_SCOPE_AGENT);
}
__device__ __forceinline__ void rpoll(const unsigned* p, unsigned tgt) {
    while (remld(p) < tgt) __builtin_amdgcn_s_sleep(2);
}

__global__ __launch_bounds__(TPB_, 1)
void rnn_wavefront(const float* __restrict__ x,
                   const float* __restrict__ W_ih0,
                   const float* __restrict__ b_ih0,
                   const float* __restrict__ W_ih,
                   const float* __restrict__ b_ih,
                   const float* __restrict__ W_hh,
                   const float* __restrict__ b_hh,
                   const float* __restrict__ W_fc,
                   const float* __restrict__ b_fc,
                   float* __restrict__ out,
                   unsigned* __restrict__ prod,    // [L_][G_]: slots exported
                   unsigned* __restrict__ cons,    // [L_][G_]: slots consumed
                   u64* __restrict__ ring,         // [L_][G_][R][RQWS_]
                   int rmask)
{
    const int l    = blockIdx.x >> 3;
    const int g    = blockIdx.x & 7;
    const int tid  = threadIdx.x;
    const int lane = tid & 63;
    const int wave = tid >> 6;          // 0..3
    const bool hrole = wave < 2;        // waves 0,1: h; waves 2,3: X
    const int whalf = wave & 1;         // h sub-index
    const int xsub  = wave - 2;         // X sub-index
    const int quad = lane >> 4;
    const int s16  = lane & 15;
    const int nbase = (hrole ? whalf : (wave - 2)) * 128;  // 128 cols per wave
    const int xtid  = tid - 128;        // X thread id 0..127 (X waves only)

    // lH: 8-deep y history (y(t) lives in lH[(t+1)&7]); wave w writes cols
    // [128w,128w+128) = k-range it OWNS as MFMA input next step.
    __shared__ __align__(16) _Float16 lH[8][BM_][SW_];
    __shared__ __align__(16) _Float16 xps[2][S_][BM_][XSW_];   // XP, lead-1
    __shared__ __align__(16) _Float16 bufX[2][BM_][SW_];       // staging ping-pong
    __shared__ __align__(16) unsigned flg[16];

    for (int i = tid; i < BM_ * SW_; i += TPB_) (&lH[0][0][0])[i] = (_Float16)0.f;
    if (tid < 16) flg[tid] = 0;

    // ---- weights: h-waves hold W_hh[l] (8 kt x 8 nt = 256 VGPR); X-waves
    // hold W_ih[l-1]. Lane holds W[n = nbase+nt*16+s16][k = kt*32+quad*8..]
    v8h wf[8][NTH_];
#pragma unroll
    for (int kt = 0; kt < 8; ++kt) {
        const int k0 = kt * 32 + quad * 8;
#pragma unroll
        for (int nt = 0; nt < NTH_; ++nt) {
            const int j = nbase + nt * 16 + s16;
            v8h w;
            if (hrole) {
                const float* src = &W_hh[(((size_t)l * H_) + j) * H_ + k0];
#pragma unroll
                for (int i = 0; i < 8; ++i) w[i] = (_Float16)src[i];
            } else if (l > 0) {
                const float* src = &W_ih[(((size_t)(l - 1) * H_) + j) * H_ + k0];
#pragma unroll
                for (int i = 0; i < 8; ++i) w[i] = (_Float16)src[i];
            } else {
#pragma unroll
                for (int i = 0; i < 8; ++i) w[i] = (_Float16)0.f;
            }
            wf[kt][nt] = w;
        }
    }

    // bias: X-waves (l>0) fold b_ih+b_hh into XP; l==0 h-waves do it locally.
    float bias[NTH_][4], w0v[NTH_][4];
    if ((hrole && l == 0) || (!hrole && l > 0)) {
#pragma unroll
        for (int nt = 0; nt < NTH_; ++nt)
#pragma unroll
            for (int r = 0; r < 4; ++r) {
                const int j = nbase + nt * 16 + quad * 4 + r;
                bias[nt][r] = b_hh[l * H_ + j] +
                              ((l == 0) ? b_ih0[j] : b_ih[(l - 1) * H_ + j]);
                w0v[nt][r]  = (l == 0) ? W_ih0[j] : 0.f;
            }
    }

    unsigned* upprod = prod + ((l > 0 ? l - 1 : 0) * G_ + g);
    unsigned* myprod = prod + (l * G_ + g);
    unsigned* mycons = cons + (l * G_ + g);
    unsigned* upcons = cons + ((l > 0 ? l - 1 : 0) * G_ + g);
    const unsigned R = (unsigned)rmask + 1u;
    u64* myring = ring + ((size_t)(l * G_ + g) * (size_t)R) * RQWS_;
    u64* upring = ring + ((size_t)((l > 0 ? l - 1 : 0) * G_ + g) * (size_t)R) * RQWS_;

    __syncthreads();   // zeros + flags visible; the only block barrier

    if (hrole) {
        // ================= h-waves: 2-wave pair recurrence =================
        float xnf[4];
        v4h xphv[4][NTH_];      // l==0 locally computed XP (hoisted at j0)
        if (l == 0) {
            const float* xrow = x + (size_t)(g * BM_ + s16) * T_;
#pragma unroll
            for (int jj = 0; jj < 4; ++jj) xnf[jj] = xrow[jj];
        }
        for (int s = 0; s < NS_; ++s) {
#pragma unroll
            for (int j = 0; j < S_; ++j) {
                const int t = 4 * s + j;
                if (j == 0) {
                    if (l > 0)      spin2(flg + F_XP, (unsigned)(s + 1)); // xps[s] ready
                    if (l < L_ - 1) spin2(flg + F_XD, (unsigned)s);       // slot s-2 exports read
                    if (l == 0) {
#pragma unroll
                        for (int jj = 0; jj < 4; ++jj)
#pragma unroll
                            for (int nt = 0; nt < NTH_; ++nt)
#pragma unroll
                                for (int r = 0; r < 4; ++r)
                                    xphv[jj][nt][r] =
                                        (_Float16)(bias[nt][r] + xnf[jj] * w0v[nt][r]);
                    }
                }
                if (j == 1 && l == 0 && s + 1 < NS_) {
                    const float* xrow = x + (size_t)(g * BM_ + s16) * T_ + 4 * (s + 1);
#pragma unroll
                    for (int jj = 0; jj < 4; ++jj) xnf[jj] = xrow[jj];
                }

                v4h xph[NTH_];
                if (l > 0) {
#pragma unroll
                    for (int nt = 0; nt < NTH_; ++nt)
                        xph[nt] = *(const v4h*)
                            &xps[s & 1][j][s16][nbase + nt * 16 + quad * 4];
                } else {
#pragma unroll
                    for (int nt = 0; nt < NTH_; ++nt) xph[nt] = xphv[j][nt];
                }

                v4f acc[NTH_];
#pragma unroll
                for (int nt = 0; nt < NTH_; ++nt) acc[nt] = (v4f){0.f, 0.f, 0.f, 0.f};

                // own k-half first (self-written, zero wait)
#pragma unroll
                for (int ko = 0; ko < 4; ++ko) {
                    const int kt = 4 * whalf + ko;
                    v8h a = *(const v8h*)&lH[t & 7][s16][kt * 32 + quad * 8];
#pragma unroll
                    for (int nt = 0; nt < NTH_; ++nt)
                        acc[nt] = __builtin_amdgcn_mfma_f32_16x16x32_f16(
                                      wf[kt][nt], a, acc[nt], 0, 0, 0);
                }
                // partner half: single-flag poll, overlapped behind own MFMAs
                spin1(&flg[F_HF + (1 - whalf)], (unsigned)t);
#pragma unroll
                for (int ko = 0; ko < 4; ++ko) {
                    const int kt = 4 * (1 - whalf) + ko;
                    v8h a = *(const v8h*)&lH[t & 7][s16][kt * 32 + quad * 8];
#pragma unroll
                    for (int nt = 0; nt < NTH_; ++nt)
                        acc[nt] = __builtin_amdgcn_mfma_f32_16x16x32_f16(
                                      wf[kt][nt], a, acc[nt], 0, 0, 0);
                }
                // epilogue: relu(XP+acc) -> lH[(t+1)&7]; one b64 per nt
#pragma unroll
                for (int nt = 0; nt < NTH_; ++nt) {
                    U64H pk;
#pragma unroll
                    for (int r = 0; r < 4; ++r) {
                        float v = (float)xph[nt][r] + acc[nt][r];
                        v = fmaxf(v, 0.f);
                        pk.h[r] = (_Float16)v;
                    }
                    *(u64*)&lH[(t + 1) & 7][s16][nbase + nt * 16 + quad * 4] = pk.u;
                }
                lgkm0();
                flagst(&flg[F_HF + whalf], (unsigned)(t + 1));
            }
        }
        if (l == L_ - 1) {
            spin2(flg + F_HF, (unsigned)T_);   // both waves wrote y(783) -> lH[0]
            lgkm0();
            for (int idx = tid; idx < BM_ * C_; idx += 128) {
                const int bl = idx / C_;
                const int c  = idx % C_;
                float sum = b_fc[c];
                for (int k = 0; k < H_; ++k)
                    sum += (float)lH[0][bl][k] * W_fc[c * H_ + k];
                out[(size_t)(g * BM_ + bl) * C_ + c] = sum;
            }
        }
    } else {
        // ============ X-waves: exports, staging, XP GEMM, protocol ============
        auto xstage = [&](const u64* sbp, int half) {   // half0: jj0,1; half1: jj2,3
            u64 sv[16];
#pragma unroll
            for (int k = 0; k < 16; ++k)
                sv[k] = ringld(sbp + (size_t)(half * 2048 + xtid + 128 * k));
#pragma unroll
            for (int k = 0; k < 16; ++k) {
                const int idx = half * 2048 + xtid + 128 * k;
                const int rr  = idx & 1023;
                *(u64*)&bufX[(idx >> 10) & 1][rr & 15][(rr >> 4) * 4] = sv[k];
            }
        };
        auto xcompute = [&](int q, int jj) {            // xps[q&1][jj] from bufX[jj&1]
            v4f xpa[NTH_];
#pragma unroll
            for (int nt = 0; nt < NTH_; ++nt)
                xpa[nt] = (v4f){bias[nt][0], bias[nt][1], bias[nt][2], bias[nt][3]};
#pragma unroll
            for (int kt = 0; kt < 8; ++kt) {
                v8h a = *(const v8h*)&bufX[jj & 1][s16][kt * 32 + quad * 8];
#pragma unroll
                for (int nt = 0; nt < NTH_; ++nt)
                    xpa[nt] = __builtin_amdgcn_mfma_f32_16x16x32_f16(
                                  wf[kt][nt], a, xpa[nt], 0, 0, 0);
            }
#pragma unroll
            for (int nt = 0; nt < NTH_; ++nt) {
                U64H pk;
#pragma unroll
                for (int r = 0; r < 4; ++r) pk.h[r] = (_Float16)xpa[nt][r];
                *(u64*)&xps[q & 1][jj][s16][nbase + nt * 16 + quad * 4] = pk.u;
            }
        };
        auto xslot = [&](int q) {                       // stage+compute slot q
            rpoll(upprod, (unsigned)(q + 1));
            spin2(flg + F_XE, (unsigned)q);             // bufX free
            const u64* sbp = upring + (size_t)(q & rmask) * RQWS_;
            xstage(sbp, 0);
            lgkm0(); flagst(&flg[F_XS + xsub], (unsigned)(2 * q + 1));
            spin2(flg + F_XS, (unsigned)(2 * q + 1));
            xcompute(q, 0); xcompute(q, 1);
            lgkm0(); flagst(&flg[F_XC + xsub], (unsigned)(q + 1));
            spin2(flg + F_XC, (unsigned)(q + 1));       // half-A reads done
            xstage(sbp, 1);
            lgkm0(); flagst(&flg[F_XS + xsub], (unsigned)(2 * q + 2));
            spin2(flg + F_XS, (unsigned)(2 * q + 2));
            xcompute(q, 2); xcompute(q, 3);
            lgkm0();
            flagst(&flg[F_XP + xsub], (unsigned)(q + 1));  // xps[q] ready
            flagst(&flg[F_XE + xsub], (unsigned)(q + 1));
        };

        if (l > 0) {                        // prologue: slot 0 -> xps[0]
            xslot(0);
            vm0();
            if (tid == 128) rempub(upcons, 1u);
        }
        for (int sg = 0; sg <= NS_; ++sg) {
            spin2s(flg + F_HF, (unsigned)(4 * sg));     // h finished superstep sg-1

            // exports: slot e = sg-1; y(t) lives in lH[(t+1)&7]; lane-contiguous
            if (l < L_ - 1 && sg >= 1) {
                const int e = sg - 1;
                if (e >= (int)R) rpoll(mycons, (unsigned)(e - (int)R + 1));
                u64* db = myring + (size_t)(e & rmask) * RQWS_;
#pragma unroll
                for (int jj = 0; jj < 4; ++jj) {
                    const int buf = (4 * e + jj + 1) & 7;
                    u64 ev[8];
#pragma unroll
                    for (int k = 0; k < 8; ++k) {
                        const int rr = xtid + 128 * k;
                        ev[k] = *(const u64*)&lH[buf][rr & 15][(rr >> 4) * 4];
                    }
#pragma unroll
                    for (int k = 0; k < 8; ++k)
                        ringst(db + (size_t)jj * 1024 + (size_t)(xtid + 128 * k), ev[k]);
                }
                lgkm0();
            }
            flagst(&flg[F_XD + xsub], (unsigned)(sg + 1));  // h may overwrite slot sg-1 bufs

            // stage + compute upstream slot sg+1 -> xps[(sg+1)&1] (lead-1)
            if (l > 0 && sg + 1 <= NS_ - 1) xslot(sg + 1);

            // drain stores/loads, rendezvous X pair, publish protocol
            vm0();
            flagst(&flg[F_XV + xsub], (unsigned)(sg + 1));
            spin2(flg + F_XV, (unsigned)(sg + 1));
            if (tid == 128) {
                if (l < L_ - 1 && sg >= 1) rempub(myprod, (unsigned)sg);
                if (l > 0 && sg + 1 <= NS_ - 1) rempub(upcons, (unsigned)(sg + 2));
            }
        }
    }
}

extern "C" void kernel_launch(void* const* d_in, const int* in_sizes, int n_in,
                              void* d_out, int out_size, void* d_ws, size_t ws_size,
                              hipStream_t stream) {
    const float* x     = (const float*)d_in[0];
    const float* W_ih0 = (const float*)d_in[1];
    const float* b_ih0 = (const float*)d_in[2];
    const float* W_ih  = (const float*)d_in[3];
    const float* b_ih  = (const float*)d_in[4];
    const float* W_hh  = (const float*)d_in[5];
    const float* b_hh  = (const float*)d_in[6];
    const float* W_fc  = (const float*)d_in[7];
    const float* b_fc  = (const float*)d_in[8];
    float* out = (float*)d_out;

    const size_t cntBytes = (size_t)L_ * G_ * sizeof(unsigned);   // 640 B each
    unsigned* prod = (unsigned*)d_ws;
    unsigned* cons = (unsigned*)((char*)d_ws + cntBytes);
    u64* ring      = (u64*)((char*)d_ws + 2 * cntBytes);

    const size_t slotBytes = (size_t)RQWS_ * 8;                   // 32 KB
    const size_t base = 2 * cntBytes;
    int R = 4;                                                    // 21 MB
    if (ws_size >= base + (size_t)L_ * G_ * 16 * slotBytes) R = 16;      // 84 MB
    else if (ws_size >= base + (size_t)L_ * G_ * 8 * slotBytes) R = 8;   // 42 MB

    (void)hipMemsetAsync(d_ws, 0, 2 * cntBytes, stream);

    rnn_wavefront<<<dim3(L_ * G_), dim3(TPB_), 0, stream>>>(
        x, W_ih0, b_ih0, W_ih, b_ih, W_hh, b_hh, W_fc, b_fc,
        out, prod, cons, ring, R - 1);
}